// Round 10
// baseline (395.091 us; speedup 1.0000x reference)
//
#include <hip/hip_runtime.h>

#define BN 4
#define NN 8192
#define EE 128
#define HH 4
#define DD 32
#define WW 33
#define QELEMS (BN*NN*EE)        // 4194304
#define WELEMS (EE*EE)           // 16384

typedef __bf16 bf16x8 __attribute__((ext_vector_type(8)));
typedef float f32x4 __attribute__((ext_vector_type(4)));
typedef unsigned short u16x8 __attribute__((ext_vector_type(8)));
typedef unsigned int u32x4 __attribute__((ext_vector_type(4)));

static __device__ __forceinline__ unsigned short f2bf(float x){
    unsigned u = __float_as_uint(x);
    u += 0x7fffu + ((u >> 16) & 1u);
    return (unsigned short)(u >> 16);
}
static __device__ __forceinline__ float bf2f(unsigned short h){
    return __uint_as_float(((unsigned)h) << 16);
}
static __device__ __forceinline__ float bflo(unsigned u){ return __uint_as_float(u << 16); }
static __device__ __forceinline__ float bfhi(unsigned u){ return __uint_as_float(u & 0xffff0000u); }
static __device__ __forceinline__ bf16x8 ld_bf8(const unsigned short* p){
    u16x8 v = *(const u16x8*)p;
    return __builtin_bit_cast(bf16x8, v);
}

// ---------------- prep: weights fp32 -> bf16 hi/lo ----------------
__global__ void __launch_bounds__(256) prep_w(const float* __restrict__ wq, const float* __restrict__ wk,
        const float* __restrict__ wv, const float* __restrict__ wo,
        unsigned short* __restrict__ wh, unsigned short* __restrict__ wl){
    int i = blockIdx.x*256 + threadIdx.x;       // 0..65535
    int sel = i >> 14;
    const float* src = (sel==0)? wq : (sel==1)? wk : (sel==2)? wv : wo;
    float x = src[i & (WELEMS-1)];
    unsigned short h = f2bf(x);
    wh[i] = h;
    wl[i] = f2bf(x - bf2f(h));
}

// ================= fully fused, LDS-packed version =================
// Block = 512 thr = 8 waves, 64 positions of one batch. LDS 80KB -> 2 blocks/CU.
// K/V/Q stored as bf16-PAIRS (u32), row stride 20 u32 -> conflict-free b128 reads.
__global__ void __launch_bounds__(512,4) fused_kernel(
        const float* __restrict__ q,
        const unsigned short* __restrict__ wh, const unsigned short* __restrict__ wl,
        const float* __restrict__ bq, const float* __restrict__ bk, const float* __restrict__ bv_,
        const float* __restrict__ bo,
        float* __restrict__ out, float* __restrict__ probs)
{
    __shared__ unsigned int L[20480];            // 80 KB
    unsigned int* Kp = L;                        // [4][96][20] u32 (bf16 pairs)
    unsigned int* Vp = L + 7680;                 // [4][96][20]
    unsigned int* Qp = L + 15360;                // [4][64][20]; later Aout [64][68]

    const int t = threadIdx.x;
    const int wv = t >> 6;               // wave 0..7 -> col stripe wv*16
    const int lane = t & 63;
    const int m = lane & 15, g = lane >> 4;
    const int b = blockIdx.y;
    const int n0 = blockIdx.x * 64;
    const size_t qrow0 = (size_t)b * NN;

    // ---- QKV B-fragments ----
    bf16x8 bH[3][4], bL[3][4];
    #pragma unroll
    for (int i=0;i<3;i++){
        const unsigned short* WH = wh + i*WELEMS + (size_t)(wv*16+m)*EE;
        const unsigned short* WL = wl + i*WELEMS + (size_t)(wv*16+m)*EE;
        #pragma unroll
        for (int kc=0;kc<4;kc++){
            bH[i][kc] = ld_bf8(WH + kc*32 + g*8);
            bL[i][kc] = ld_bf8(WL + kc*32 + g*8);
        }
    }
    const float bias3[3] = { bq[wv*16+m], bk[wv*16+m], bv_[wv*16+m] };
    const int head = wv >> 1;
    const int ucol = (wv & 1)*8 + (m >> 1);      // u32-col 0..15 within head (pairs)

    // ---- Phase A: QKV for halo rows [n0-16, n0+80) -> packed LDS ----
    float4 fa[2][8];
    {
        int grow = n0 - 16 + m;
        bool ok = (grow >= 0) && (grow < NN);
        const float* qp = q + (qrow0 + (ok ? grow : 0))*EE;
        #pragma unroll
        for (int kc=0;kc<4;kc++){
            fa[0][kc*2]   = ok ? *(const float4*)(qp + kc*32 + g*8)     : make_float4(0.f,0.f,0.f,0.f);
            fa[0][kc*2+1] = ok ? *(const float4*)(qp + kc*32 + g*8 + 4) : make_float4(0.f,0.f,0.f,0.f);
        }
    }
    #pragma unroll
    for (int tile=0; tile<6; tile++){
        if (tile < 5){
            int grow = n0 - 16 + (tile+1)*16 + m;
            bool ok = (grow >= 0) && (grow < NN);
            const float* qp = q + (qrow0 + (ok ? grow : 0))*EE;
            #pragma unroll
            for (int kc=0;kc<4;kc++){
                fa[(tile+1)&1][kc*2]   = ok ? *(const float4*)(qp + kc*32 + g*8)     : make_float4(0.f,0.f,0.f,0.f);
                fa[(tile+1)&1][kc*2+1] = ok ? *(const float4*)(qp + kc*32 + g*8 + 4) : make_float4(0.f,0.f,0.f,0.f);
            }
        }
        bf16x8 aH[4], aL[4];
        #pragma unroll
        for (int kc=0;kc<4;kc++){
            float4 v0 = fa[tile&1][kc*2], v1 = fa[tile&1][kc*2+1];
            float vvv[8] = {v0.x,v0.y,v0.z,v0.w,v1.x,v1.y,v1.z,v1.w};
            u16x8 hh, ll;
            #pragma unroll
            for (int j=0;j<8;j++){
                unsigned short hB = f2bf(vvv[j]);
                hh[j] = hB;
                ll[j] = f2bf(vvv[j] - bf2f(hB));
            }
            aH[kc] = __builtin_bit_cast(bf16x8, hh);
            aL[kc] = __builtin_bit_cast(bf16x8, ll);
        }
        #pragma unroll
        for (int i=0;i<3;i++){
            if (i==0 && (tile==0 || tile==5)) continue;   // Q only rows 16..79
            f32x4 acc = {0.f,0.f,0.f,0.f};
            #pragma unroll
            for (int kc=0;kc<4;kc++){
                acc = __builtin_amdgcn_mfma_f32_16x16x32_bf16(aH[kc], bH[i][kc], acc, 0,0,0);
                acc = __builtin_amdgcn_mfma_f32_16x16x32_bf16(aH[kc], bL[i][kc], acc, 0,0,0);
                acc = __builtin_amdgcn_mfma_f32_16x16x32_bf16(aL[kc], bH[i][kc], acc, 0,0,0);
            }
            #pragma unroll
            for (int r=0;r<4;r++){
                int hrow = tile*16 + g*4 + r;             // 0..95
                int grow = n0 - 16 + hrow;
                bool inr = (grow >= 0) && (grow < NN);
                float val = acc[r] + (inr ? bias3[i] : 0.f);
                unsigned own = f2bf(val);                 // bf16 (pad rows exact 0)
                unsigned nb  = (unsigned)__shfl_xor((int)own, 1);
                if (!(lane & 1)){                         // even m packs (dim, dim+1)
                    unsigned pk = own | (nb << 16);
                    if (i==0)      Qp[(head*64 + hrow-16)*20 + ucol] = pk;
                    else if (i==1) Kp[(head*96 + hrow   )*20 + ucol] = pk;
                    else           Vp[(head*96 + hrow   )*20 + ucol] = pk;
                }
            }
        }
    }
    __syncthreads();

    // ---- Phase B: attention; thread (p,h,e) owns ww range e*17.. ----
    const int pr = t >> 1, e = t & 1;
    const int p = pr & 63, h = pr >> 6;

    float qf[32];
    {
        const unsigned int* qb = Qp + (h*64 + p)*20;
        #pragma unroll
        for (int i=0;i<4;i++){
            u32x4 v = *(const u32x4*)(qb + i*4);
            #pragma unroll
            for (int j=0;j<4;j++){
                qf[i*8 + j*2]     = bflo(v[j]);
                qf[i*8 + j*2 + 1] = bfhi(v[j]);
            }
        }
    }
    __syncthreads();   // all Q reads done before Aout aliases Qp

    const int wbase = e * 17;
    float sc[17];
    {
        const unsigned int* kb = Kp + (h*96 + p + wbase)*20;
        #pragma unroll
        for (int j=0;j<17;j++){
            if (j==16 && e==1){ sc[16] = 0.f; continue; }
            float s0=0.f, s1=0.f, s2=0.f, s3=0.f;
            #pragma unroll
            for (int i=0;i<4;i++){
                u32x4 kv = *(const u32x4*)(kb + j*20 + i*4);
                s0 = fmaf(qf[i*8+0], bflo(kv[0]), s0);
                s1 = fmaf(qf[i*8+1], bfhi(kv[0]), s1);
                s2 = fmaf(qf[i*8+2], bflo(kv[1]), s2);
                s3 = fmaf(qf[i*8+3], bfhi(kv[1]), s3);
                s0 = fmaf(qf[i*8+4], bflo(kv[2]), s0);
                s1 = fmaf(qf[i*8+5], bfhi(kv[2]), s1);
                s2 = fmaf(qf[i*8+6], bflo(kv[3]), s2);
                s3 = fmaf(qf[i*8+7], bfhi(kv[3]), s3);
            }
            sc[j] = ((s0+s1)+(s2+s3)) * 0.17677669529663687f;   // 1/sqrt(32)
        }
    }
    float mloc = -1e30f;
    #pragma unroll
    for (int j=0;j<17;j++){ if (j==16 && e==1) continue; mloc = fmaxf(mloc, sc[j]); }
    float mall = fmaxf(mloc, __shfl_xor(mloc, 1));
    float sloc = 0.f;
    #pragma unroll
    for (int j=0;j<17;j++){ if (j==16 && e==1) continue; sc[j] = __expf(sc[j]-mall); sloc += sc[j]; }
    float inv = 1.f / (sloc + __shfl_xor(sloc, 1));
    #pragma unroll
    for (int j=0;j<17;j++) sc[j] *= inv;

    // probs direct (compile-time indices; j==16 only for e==0)
    {
        float* pp = probs + ((size_t)(b*HH + h)*NN + n0 + p)*WW + wbase;
        #pragma unroll
        for (int j=0;j<16;j++) pp[j] = sc[j];
        if (e==0) pp[16] = sc[16];
    }

    // PV over own ww range, full 32 dims
    float pv[32];
    #pragma unroll
    for (int k=0;k<32;k++) pv[k] = 0.f;
    {
        const unsigned int* vb = Vp + (h*96 + p + wbase)*20;
        #pragma unroll
        for (int j=0;j<17;j++){
            if (j==16 && e==1) continue;
            float pw = sc[j];
            #pragma unroll
            for (int i=0;i<4;i++){
                u32x4 vx = *(const u32x4*)(vb + j*20 + i*4);
                pv[i*8+0] = fmaf(pw, bflo(vx[0]), pv[i*8+0]);
                pv[i*8+1] = fmaf(pw, bfhi(vx[0]), pv[i*8+1]);
                pv[i*8+2] = fmaf(pw, bflo(vx[1]), pv[i*8+2]);
                pv[i*8+3] = fmaf(pw, bfhi(vx[1]), pv[i*8+3]);
                pv[i*8+4] = fmaf(pw, bflo(vx[2]), pv[i*8+4]);
                pv[i*8+5] = fmaf(pw, bfhi(vx[2]), pv[i*8+5]);
                pv[i*8+6] = fmaf(pw, bflo(vx[3]), pv[i*8+6]);
                pv[i*8+7] = fmaf(pw, bfhi(vx[3]), pv[i*8+7]);
            }
        }
    }
    #pragma unroll
    for (int k=0;k<32;k++) pv[k] += __shfl_xor(pv[k], 1);

    // attn-out -> Aout (alias Qp): [64 rows][68 u32], plain bf16 pairs.
    // Thread stores u32-cols h*16 + e*8 .. +8 (dims h*32+e*16 .. +16).
    unsigned int* Ao = Qp;
    {
        u32x4 a0, a1;
        if (e==0){
            #pragma unroll
            for (int k=0;k<4;k++) a0[k] = (unsigned)f2bf(pv[2*k])   | ((unsigned)f2bf(pv[2*k+1])   << 16);
            #pragma unroll
            for (int k=0;k<4;k++) a1[k] = (unsigned)f2bf(pv[8+2*k]) | ((unsigned)f2bf(pv[8+2*k+1]) << 16);
        } else {
            #pragma unroll
            for (int k=0;k<4;k++) a0[k] = (unsigned)f2bf(pv[16+2*k]) | ((unsigned)f2bf(pv[16+2*k+1]) << 16);
            #pragma unroll
            for (int k=0;k<4;k++) a1[k] = (unsigned)f2bf(pv[24+2*k]) | ((unsigned)f2bf(pv[24+2*k+1]) << 16);
        }
        unsigned int* ap = Ao + p*68 + h*16 + e*8;
        *(u32x4*)(ap)     = a0;
        *(u32x4*)(ap + 4) = a1;
    }
    __syncthreads();

    // ---- Phase C: out = attnout @ Wo^T + bo (A plain bf16, B hi/lo) ----
    bf16x8 cH[4], cL[4];
    {
        const unsigned short* WH = wh + 3*WELEMS + (size_t)(wv*16+m)*EE;
        const unsigned short* WL = wl + 3*WELEMS + (size_t)(wv*16+m)*EE;
        #pragma unroll
        for (int kc=0;kc<4;kc++){
            cH[kc] = ld_bf8(WH + kc*32 + g*8);
            cL[kc] = ld_bf8(WL + kc*32 + g*8);
        }
    }
    const float bov = bo[wv*16+m];

    #pragma unroll
    for (int rt=0; rt<4; rt++){
        f32x4 acc2 = {0.f,0.f,0.f,0.f};
        #pragma unroll
        for (int kc=0;kc<4;kc++){
            u32x4 a4 = *(const u32x4*)(Ao + (rt*16+m)*68 + kc*16 + g*4);
            bf16x8 afr = __builtin_bit_cast(bf16x8, a4);
            acc2 = __builtin_amdgcn_mfma_f32_16x16x32_bf16(afr, cH[kc], acc2, 0,0,0);
            acc2 = __builtin_amdgcn_mfma_f32_16x16x32_bf16(afr, cL[kc], acc2, 0,0,0);
        }
        float* op = out + (qrow0 + n0 + rt*16 + g*4)*EE + wv*16 + m;
        #pragma unroll
        for (int r=0;r<4;r++) op[(size_t)r*EE] = acc2[r] + bov;
    }
}

extern "C" void kernel_launch(void* const* d_in, const int* in_sizes, int n_in,
                              void* d_out, int out_size, void* d_ws, size_t ws_size,
                              hipStream_t stream) {
    const float* q  = (const float*)d_in[0];
    const float* Wq = (const float*)d_in[1];  const float* bq = (const float*)d_in[2];
    const float* Wk = (const float*)d_in[3];  const float* bk = (const float*)d_in[4];
    const float* Wv = (const float*)d_in[5];  const float* bv = (const float*)d_in[6];
    const float* Wo = (const float*)d_in[7];  const float* bo = (const float*)d_in[8];

    float* out   = (float*)d_out;             // (B,N,E)
    float* probs = out + QELEMS;              // (B,H,N,W)

    unsigned short* w_hi = (unsigned short*)d_ws;
    unsigned short* w_lo = w_hi + 4*WELEMS;

    prep_w<<<4*WELEMS/256, 256, 0, stream>>>(Wq, Wk, Wv, Wo, w_hi, w_lo);
    fused_kernel<<<dim3(NN/64, BN), 512, 0, stream>>>(q, w_hi, w_lo,
                                                      bq, bk, bv, bo, out, probs);
}